// Round 9
// baseline (173.248 us; speedup 1.0000x reference)
//
#include <hip/hip_runtime.h>

// Problem: B=32, N=128, T=96, H=64, TF=24. All I/O float32.
// A_norm = ones(N,N)/N => every GCN output is the node-mean (node-uniform);
// model collapses to per-batch H-vectors. Node dim appears only in the
// initial mean and the final broadcast.
//
// R8 post-mortem: LDS-weight and global-weight ODE time IDENTICALLY =>
// bottleneck is unhidden load latency (~8 loads in flight => ~120cyc stall
// per 8 MACs => ~13cyc/MAC), not the weight source. This version software-
// pipelines the ODE matvec explicitly: double-buffered 8-float chunks
// prefetched from LDS one chunk ahead of the compute. Plus rcp-based
// tanh/sigmoid (precise div was on the 184-layer serial path).

#define BN 32
#define NN 128
#define TT 96
#define HH 64
#define TFC 24

__device__ __forceinline__ float rdl(float v, int l) {
    return __int_as_float(__builtin_amdgcn_readlane(__float_as_int(v), l));
}
__device__ __forceinline__ float fast_tanh(float x) {
    x = fminf(fmaxf(x, -15.f), 15.f);
    float e = __expf(2.f * x);                    // v_exp_f32 (+mul)
    return 1.f - 2.f * __builtin_amdgcn_rcpf(e + 1.f);  // v_rcp: skip slow div
}
__device__ __forceinline__ float fast_sigmoid(float x) {
    return __builtin_amdgcn_rcpf(1.f + __expf(-x));
}
__device__ __forceinline__ float wave_sum(float v) {
#pragma unroll
    for (int off = 32; off > 0; off >>= 1) v += __shfl_xor(v, off, 64);
    return v;
}
__device__ __forceinline__ float wave_max(float v) {
#pragma unroll
    for (int off = 32; off > 0; off >>= 1) v = fmaxf(v, __shfl_xor(v, off, 64));
    return v;
}

__global__ __launch_bounds__(256)
__attribute__((amdgpu_waves_per_eu(1, 1)))
void fused_kernel(
    const float* __restrict__ x,    const float* __restrict__ Ws1,
    const float* __restrict__ bs1,  const float* __restrict__ Ws2,
    const float* __restrict__ bs2,  const float* __restrict__ Wa1,
    const float* __restrict__ ba1,  const float* __restrict__ Wa2,
    const float* __restrict__ Wih,  const float* __restrict__ bih,
    const float* __restrict__ bhh,  const float* __restrict__ Wo1,
    const float* __restrict__ bo1p, const float* __restrict__ Wo2,
    const float* __restrict__ bo2p, const float* __restrict__ Wout,
    const float* __restrict__ boutp, float* __restrict__ out)
{
    const int tid  = threadIdx.x;
    const int lane = tid & 63;
    const int w    = tid >> 6;
    const int b    = blockIdx.x;

    __shared__ float xbar[TT];
    __shared__ float h2s[TT][HH];
    __shared__ float atts[TT];
    __shared__ float wo1_l[HH * HH];   // [h][j] ODE layer-1 weights (16KB)
    __shared__ float wo2_l[HH * HH];   // [h][j] ODE layer-2 weights (16KB)

    // ---- stage ODE weights into LDS (coalesced float4, all 256 threads) ----
#pragma unroll
    for (int i = 0; i < 4; ++i) {
        const int idx = (i * 256 + tid) * 4;
        *(float4*)&wo1_l[idx] = *(const float4*)&Wo1[idx];
        *(float4*)&wo2_l[idx] = *(const float4*)&Wo2[idx];
    }

    // ---- phase 0: xbar[t] = mean_n x[b,n,t] ----
    if (tid < TT) {
        const float* xb = x + (size_t)b * NN * TT + tid;
        float s = 0.f;
#pragma unroll
        for (int n = 0; n < NN; ++n) s += xb[n * TT];
        xbar[tid] = s * (1.f / 128.f);
    }

    {   // ---- phase 1: spatial GCN + attention logits (4 waves, 24 t each) --
        const float ws1l = Ws1[lane];
        const float bs1l = bs1[lane];
        const float bs2l = bs2[lane];
        const float ba1l = ba1[lane];
        const float wa2l = Wa2[lane];
        float ws2c[HH], wa1c[HH];
#pragma unroll
        for (int h = 0; h < HH; ++h) {
            ws2c[h] = Ws2[h * HH + lane];
            wa1c[h] = Wa1[h * HH + lane];
        }
        __syncthreads();   // barrier 1: xbar + staged LDS weights ready

#pragma unroll 1
        for (int i = 0; i < TT / 4; ++i) {
            const int t = w * (TT / 4) + i;
            const float s = xbar[t];
            const float h1 = fmaxf(fmaf(s, ws1l, bs1l), 0.f);  // lane = h
            float a0 = bs2l, a1 = 0.f, a2 = 0.f, a3 = 0.f;
#pragma unroll
            for (int h = 0; h < HH; h += 4) {
                a0 = fmaf(rdl(h1, h),     ws2c[h],     a0);
                a1 = fmaf(rdl(h1, h + 1), ws2c[h + 1], a1);
                a2 = fmaf(rdl(h1, h + 2), ws2c[h + 2], a2);
                a3 = fmaf(rdl(h1, h + 3), ws2c[h + 3], a3);
            }
            const float h2v = fmaxf((a0 + a1) + (a2 + a3), 0.f);
            h2s[t][lane] = h2v;

            a0 = ba1l; a1 = 0.f; a2 = 0.f; a3 = 0.f;
#pragma unroll
            for (int h = 0; h < HH; h += 4) {
                a0 = fmaf(rdl(h2v, h),     wa1c[h],     a0);
                a1 = fmaf(rdl(h2v, h + 1), wa1c[h + 1], a1);
                a2 = fmaf(rdl(h2v, h + 2), wa1c[h + 2], a2);
                a3 = fmaf(rdl(h2v, h + 3), wa1c[h + 3], a3);
            }
            const float g = fast_tanh((a0 + a1) + (a2 + a3));
            const float att = wave_sum(g * wa2l);   // ba2: shift-invariant
            if (lane == 0) atts[t] = att;
        }
    }
    __syncthreads();   // barrier 2: h2s, atts ready

    if (w != 0) return;   // waves 1-3 retire; wave 0 owns the LDS pipe

    // ================= wave 0 only: softmax + nf + GRU + ODE =================
    const float a0s = atts[lane];
    const float a1s = (lane < TT - 64) ? atts[64 + lane] : -1e30f;
    const float m = wave_max(fmaxf(a0s, a1s));
    const float e0 = __expf(a0s - m);
    const float e1 = (lane < TT - 64) ? __expf(a1s - m) : 0.f;
    const float inv = __builtin_amdgcn_rcpf(wave_sum(e0 + e1));
    const float q0 = e0 * inv;
    const float q1 = e1 * inv;

    float nf = 0.f;
#pragma unroll
    for (int t = 0; t < 64; ++t) nf = fmaf(rdl(q0, t), h2s[t][lane], nf);
#pragma unroll
    for (int t = 0; t < 32; ++t) nf = fmaf(rdl(q1, t), h2s[64 + t][lane], nf);

    // one-step GRU, h0=0 (W_hh matmul vanishes; b_hh biases remain)
    float gr = bih[lane];
    float gz = bih[64 + lane];
    float gn = bih[128 + lane];
#pragma unroll
    for (int j = 0; j < HH; j += 4) {
        const float4 wr = *(const float4*)&Wih[(size_t)lane * HH + j];
        const float4 wz = *(const float4*)&Wih[(size_t)(64 + lane) * HH + j];
        const float4 wn = *(const float4*)&Wih[(size_t)(128 + lane) * HH + j];
        const float n0 = rdl(nf, j), n1 = rdl(nf, j + 1);
        const float n2 = rdl(nf, j + 2), n3 = rdl(nf, j + 3);
        gr += n0 * wr.x + n1 * wr.y + n2 * wr.z + n3 * wr.w;
        gz += n0 * wz.x + n1 * wz.y + n2 * wz.z + n3 * wz.w;
        gn += n0 * wn.x + n1 * wn.y + n2 * wn.z + n3 * wn.w;
    }
    const float r = fast_sigmoid(gr + bhh[lane]);
    const float z = fast_sigmoid(gz + bhh[64 + lane]);
    const float n = fast_tanh(gn + r * bhh[128 + lane]);
    float y = (1.f - z) * n;

    const float bo1 = bo1p[lane];
    const float bo2 = bo2p[lane];
    const float wo  = Wout[lane];
    const float bo  = boutp[0];

    // One matvec layer from LDS weights, software-pipelined:
    // double-buffered 8-float chunks, prefetch chunk c+1 while computing c.
    auto layer = [&](const float* Wl, float u, float bias) -> float {
        float bufA[8], bufB[8];
#pragma unroll
        for (int k = 0; k < 8; ++k) bufA[k] = Wl[k * HH + lane];
        float c0 = bias, c1 = 0.f, c2 = 0.f, c3 = 0.f;
#pragma unroll
        for (int ch = 0; ch < 8; ++ch) {
            float* cur = (ch & 1) ? bufB : bufA;
            float* nxt = (ch & 1) ? bufA : bufB;
            if (ch < 7) {
#pragma unroll
                for (int k = 0; k < 8; ++k)
                    nxt[k] = Wl[(ch * 8 + 8 + k) * HH + lane];
            }
            const int hb = ch * 8;
            c0 = fmaf(rdl(u, hb + 0), cur[0], c0);
            c1 = fmaf(rdl(u, hb + 1), cur[1], c1);
            c2 = fmaf(rdl(u, hb + 2), cur[2], c2);
            c3 = fmaf(rdl(u, hb + 3), cur[3], c3);
            c0 = fmaf(rdl(u, hb + 4), cur[4], c0);
            c1 = fmaf(rdl(u, hb + 5), cur[5], c1);
            c2 = fmaf(rdl(u, hb + 6), cur[6], c2);
            c3 = fmaf(rdl(u, hb + 7), cur[7], c3);
        }
        return (c0 + c1) + (c2 + c3);
    };

    auto f_eval = [&](float u) -> float {
        const float v = fast_tanh(layer(wo1_l, u, bo1));
        return fast_tanh(layer(wo2_l, v, bo2));
    };

    // output head: p is uniform across lanes after wave_sum; store directly.
    float* ob = out + (size_t)b * NN * TFC;
    {
        const float p = wave_sum(y * wo) + bo;     // traj[0] = hidden
        ob[lane * TFC]        = p;                 // n = lane
        ob[(64 + lane) * TFC] = p;                 // n = lane+64
    }

    const float dt = (float)(24.0 / 23.0);
    const float third = 1.f / 3.f;

#pragma unroll 1
    for (int st = 0; st < TFC - 1; ++st) {
        const float k1 = f_eval(y);
        const float k2 = f_eval(y + dt * k1 * third);
        const float k3 = f_eval(y + dt * (k2 - k1 * third));
        const float k4 = f_eval(y + dt * (k1 - k2 + k3));
        y = y + dt * (k1 + 3.f * (k2 + k3) + k4) * 0.125f;
        const float p = wave_sum(y * wo) + bo;
        ob[lane * TFC + st + 1]        = p;
        ob[(64 + lane) * TFC + st + 1] = p;
    }
}

extern "C" void kernel_launch(void* const* d_in, const int* in_sizes, int n_in,
                              void* d_out, int out_size, void* d_ws, size_t ws_size,
                              hipStream_t stream) {
    (void)in_sizes; (void)n_in; (void)d_ws; (void)ws_size; (void)out_size;
    const float* x    = (const float*)d_in[0];
    const float* Ws1  = (const float*)d_in[1];
    const float* bs1  = (const float*)d_in[2];
    const float* Ws2  = (const float*)d_in[3];
    const float* bs2  = (const float*)d_in[4];
    const float* Wa1  = (const float*)d_in[5];
    const float* ba1  = (const float*)d_in[6];
    const float* Wa2  = (const float*)d_in[7];
    // d_in[8]  = ba2  : unused (softmax shift-invariant)
    const float* Wih  = (const float*)d_in[9];
    // d_in[10] = W_hh : unused (h0 = 0)
    const float* bih  = (const float*)d_in[11];
    const float* bhh  = (const float*)d_in[12];
    const float* Wo1  = (const float*)d_in[13];
    const float* bo1  = (const float*)d_in[14];
    const float* Wo2  = (const float*)d_in[15];
    const float* bo2  = (const float*)d_in[16];
    const float* Wout = (const float*)d_in[17];
    const float* bout = (const float*)d_in[18];

    fused_kernel<<<dim3(BN), dim3(256), 0, stream>>>(
        x, Ws1, bs1, Ws2, bs2, Wa1, ba1, Wa2,
        Wih, bih, bhh, Wo1, bo1, Wo2, bo2, Wout, bout,
        (float*)d_out);
}

// Round 11
// 148.713 us; speedup vs baseline: 1.1650x; 1.1650x over previous
//
#include <hip/hip_runtime.h>

// Problem: B=32, N=128, T=96, H=64, TF=24. All I/O float32.
// A_norm = ones(N,N)/N => every GCN output is the node-mean (node-uniform);
// model collapses to per-batch H-vectors. Node dim only in the initial mean
// and the final broadcast.
//
// R8/R9 post-mortem: any memory source in the 184-layer serial ODE chain
// runs at latency rate (~950 cyc/layer vs ~400 issue model); compiler won't
// pipeline deep enough. This version removes memory from the chain: weights
// live in registers as PACKED f16 pairs (32 VGPRs/matrix => fits the ~132
// cap that doomed fp32 residency), state is packed once per layer via
// cvt_pkrtz + shfl_xor(1), and each weight pair is one readlane + one
// v_dot2_f32_f16 (f32 accumulate). Zero loads, zero barriers in the chain.
// R10 fix: cvt_pkrtz/fdot2 use __fp16 ext-vector, not _Float16.

#define BN 32
#define NN 128
#define TT 96
#define HH 64
#define TFC 24

#if defined(__has_builtin)
#if __has_builtin(__builtin_amdgcn_fdot2)
#define HAVE_FDOT2 1
#endif
#endif

using half2v = __fp16 __attribute__((ext_vector_type(2)));

__device__ __forceinline__ unsigned pack_pair(float a, float b) {
    union { half2v h; unsigned u; } c;
    c.h = __builtin_amdgcn_cvt_pkrtz(a, b);
    return c.u;
}
__device__ __forceinline__ half2v as_h2(unsigned u) {
    union { unsigned u; half2v h; } c; c.u = u; return c.h;
}
__device__ __forceinline__ unsigned rdlu(unsigned v, int l) {
    return (unsigned)__builtin_amdgcn_readlane((int)v, l);
}
__device__ __forceinline__ float rdl(float v, int l) {
    return __int_as_float(__builtin_amdgcn_readlane(__float_as_int(v), l));
}
__device__ __forceinline__ float dot2acc(unsigned w, unsigned up, float acc) {
#if HAVE_FDOT2
    return __builtin_amdgcn_fdot2(as_h2(w), as_h2(up), acc, false);
#else
    const half2v wh = as_h2(w), uh = as_h2(up);
    return fmaf((float)wh.y, (float)uh.y, fmaf((float)wh.x, (float)uh.x, acc));
#endif
}

// 64-MAC matvec from packed-f16 register weights. UPACK holds (u[2k],u[2k+1])
// in even lane 2k (built once per matvec). Fully unrolled, constant indices.
#define PMV64(WP, UPACK, RES)                                              \
    do {                                                                   \
        float c0 = 0.f, c1 = 0.f, c2 = 0.f, c3 = 0.f;                      \
        _Pragma("unroll")                                                  \
        for (int k = 0; k < 32; k += 4) {                                  \
            c0 = dot2acc(WP[k],     rdlu(UPACK, 2 * k),     c0);           \
            c1 = dot2acc(WP[k + 1], rdlu(UPACK, 2 * k + 2), c1);           \
            c2 = dot2acc(WP[k + 2], rdlu(UPACK, 2 * k + 4), c2);           \
            c3 = dot2acc(WP[k + 3], rdlu(UPACK, 2 * k + 6), c3);           \
        }                                                                  \
        RES = (c0 + c1) + (c2 + c3);                                       \
    } while (0)

__device__ __forceinline__ float fast_tanh(float x) {
    x = fminf(fmaxf(x, -15.f), 15.f);
    float e = __expf(2.f * x);
    return 1.f - 2.f * __builtin_amdgcn_rcpf(e + 1.f);
}
__device__ __forceinline__ float fast_sigmoid(float x) {
    return __builtin_amdgcn_rcpf(1.f + __expf(-x));
}
__device__ __forceinline__ float wave_sum(float v) {
#pragma unroll
    for (int off = 32; off > 0; off >>= 1) v += __shfl_xor(v, off, 64);
    return v;
}
__device__ __forceinline__ float wave_max(float v) {
#pragma unroll
    for (int off = 32; off > 0; off >>= 1) v = fmaxf(v, __shfl_xor(v, off, 64));
    return v;
}

__global__ __launch_bounds__(256)
__attribute__((amdgpu_waves_per_eu(1, 1)))
void fused_kernel(
    const float* __restrict__ x,    const float* __restrict__ Ws1,
    const float* __restrict__ bs1,  const float* __restrict__ Ws2,
    const float* __restrict__ bs2,  const float* __restrict__ Wa1,
    const float* __restrict__ ba1,  const float* __restrict__ Wa2,
    const float* __restrict__ Wih,  const float* __restrict__ bih,
    const float* __restrict__ bhh,  const float* __restrict__ Wo1,
    const float* __restrict__ bo1p, const float* __restrict__ Wo2,
    const float* __restrict__ bo2p, const float* __restrict__ Wout,
    const float* __restrict__ boutp, float* __restrict__ out)
{
    const int tid  = threadIdx.x;
    const int lane = tid & 63;
    const int w    = tid >> 6;
    const int b    = blockIdx.x;

    __shared__ float xbar[TT];
    __shared__ float h2s[TT][HH];
    __shared__ float atts[TT];

    // ---- phase 0: xbar[t] = mean_n x[b,n,t] ----
    if (tid < TT) {
        const float* xb = x + (size_t)b * NN * TT + tid;
        float s = 0.f;
#pragma unroll
        for (int n = 0; n < NN; ++n) s += xb[n * TT];
        xbar[tid] = s * (1.f / 128.f);
    }

    {   // ---- phase 1: spatial GCN + attention logits, packed-f16 weights ----
        const float ws1l = Ws1[lane];
        const float bs1l = bs1[lane];
        const float bs2l = bs2[lane];
        const float ba1l = ba1[lane];
        const float wa2l = Wa2[lane];
        unsigned ws2p[32], wa1p[32];
#pragma unroll
        for (int k = 0; k < 32; ++k) {
            ws2p[k] = pack_pair(Ws2[(2 * k) * HH + lane], Ws2[(2 * k + 1) * HH + lane]);
            wa1p[k] = pack_pair(Wa1[(2 * k) * HH + lane], Wa1[(2 * k + 1) * HH + lane]);
        }
#pragma unroll
        for (int k = 0; k < 32; ++k) {
            asm volatile("" : "+v"(ws2p[k]), "+v"(wa1p[k]));  // pin: 64 VGPRs
        }
        __syncthreads();   // barrier 1: xbar ready

#pragma unroll 1
        for (int i = 0; i < TT / 4; ++i) {
            const int t = w * (TT / 4) + i;
            const float s = xbar[t];
            const float h1 = fmaxf(fmaf(s, ws1l, bs1l), 0.f);  // lane = h
            const unsigned up1 = pack_pair(h1, __shfl_xor(h1, 1, 64));
            float acc;
            PMV64(ws2p, up1, acc);
            const float h2v = fmaxf(acc + bs2l, 0.f);
            h2s[t][lane] = h2v;

            const unsigned up2 = pack_pair(h2v, __shfl_xor(h2v, 1, 64));
            PMV64(wa1p, up2, acc);
            const float g = fast_tanh(acc + ba1l);
            const float att = wave_sum(g * wa2l);   // ba2: shift-invariant
            if (lane == 0) atts[t] = att;
        }
    }
    __syncthreads();   // barrier 2: h2s, atts ready

    if (w != 0) return;   // waves 1-3 retire

    // ================= wave 0 only: softmax + nf + GRU + ODE =================
    const float a0s = atts[lane];
    const float a1s = (lane < TT - 64) ? atts[64 + lane] : -1e30f;
    const float m = wave_max(fmaxf(a0s, a1s));
    const float e0 = __expf(a0s - m);
    const float e1 = (lane < TT - 64) ? __expf(a1s - m) : 0.f;
    const float inv = __builtin_amdgcn_rcpf(wave_sum(e0 + e1));
    const float q0 = e0 * inv;
    const float q1 = e1 * inv;

    float nf = 0.f;
#pragma unroll
    for (int t = 0; t < 64; ++t) nf = fmaf(rdl(q0, t), h2s[t][lane], nf);
#pragma unroll
    for (int t = 0; t < 32; ++t) nf = fmaf(rdl(q1, t), h2s[64 + t][lane], nf);

    // one-step GRU, h0=0 (W_hh matmul vanishes; b_hh biases remain)
    float gr = bih[lane];
    float gz = bih[64 + lane];
    float gn = bih[128 + lane];
#pragma unroll
    for (int j = 0; j < HH; j += 4) {
        const float4 wr = *(const float4*)&Wih[(size_t)lane * HH + j];
        const float4 wz = *(const float4*)&Wih[(size_t)(64 + lane) * HH + j];
        const float4 wn = *(const float4*)&Wih[(size_t)(128 + lane) * HH + j];
        const float n0 = rdl(nf, j), n1 = rdl(nf, j + 1);
        const float n2 = rdl(nf, j + 2), n3 = rdl(nf, j + 3);
        gr += n0 * wr.x + n1 * wr.y + n2 * wr.z + n3 * wr.w;
        gz += n0 * wz.x + n1 * wz.y + n2 * wz.z + n3 * wz.w;
        gn += n0 * wn.x + n1 * wn.y + n2 * wn.z + n3 * wn.w;
    }
    const float r = fast_sigmoid(gr + bhh[lane]);
    const float z = fast_sigmoid(gz + bhh[64 + lane]);
    const float n = fast_tanh(gn + r * bhh[128 + lane]);
    float y = (1.f - z) * n;

    // ---- ODE weights: packed f16 into 64 pinned VGPRs (fits ~132 cap) ----
    unsigned w1p[32], w2p[32];
#pragma unroll
    for (int k = 0; k < 32; ++k) {
        w1p[k] = pack_pair(Wo1[(2 * k) * HH + lane], Wo1[(2 * k + 1) * HH + lane]);
        w2p[k] = pack_pair(Wo2[(2 * k) * HH + lane], Wo2[(2 * k + 1) * HH + lane]);
    }
#pragma unroll
    for (int k = 0; k < 32; ++k) {
        asm volatile("" : "+v"(w1p[k]), "+v"(w2p[k]));
    }
    const float bo1 = bo1p[lane];
    const float bo2 = bo2p[lane];
    const float wo  = Wout[lane];
    const float bo  = boutp[0];

    // f(u) = tanh( tanh(u@W1+b1) @ W2 + b2 ) — pure VALU, no memory.
    auto f_eval = [&](float u) -> float {
        const unsigned upA = pack_pair(u, __shfl_xor(u, 1, 64));
        float acc;
        PMV64(w1p, upA, acc);
        const float v = fast_tanh(acc + bo1);
        const unsigned upB = pack_pair(v, __shfl_xor(v, 1, 64));
        PMV64(w2p, upB, acc);
        return fast_tanh(acc + bo2);
    };

    float* ob = out + (size_t)b * NN * TFC;
    {
        const float p = wave_sum(y * wo) + bo;     // traj[0] = hidden
        ob[lane * TFC]        = p;
        ob[(64 + lane) * TFC] = p;
    }

    const float dt = (float)(24.0 / 23.0);
    const float third = 1.f / 3.f;

#pragma unroll 1
    for (int st = 0; st < TFC - 1; ++st) {
        const float k1 = f_eval(y);
        const float k2 = f_eval(y + dt * k1 * third);
        const float k3 = f_eval(y + dt * (k2 - k1 * third));
        const float k4 = f_eval(y + dt * (k1 - k2 + k3));
        y = y + dt * (k1 + 3.f * (k2 + k3) + k4) * 0.125f;
        const float p = wave_sum(y * wo) + bo;
        ob[lane * TFC + st + 1]        = p;
        ob[(64 + lane) * TFC + st + 1] = p;
    }
}

extern "C" void kernel_launch(void* const* d_in, const int* in_sizes, int n_in,
                              void* d_out, int out_size, void* d_ws, size_t ws_size,
                              hipStream_t stream) {
    (void)in_sizes; (void)n_in; (void)d_ws; (void)ws_size; (void)out_size;
    const float* x    = (const float*)d_in[0];
    const float* Ws1  = (const float*)d_in[1];
    const float* bs1  = (const float*)d_in[2];
    const float* Ws2  = (const float*)d_in[3];
    const float* bs2  = (const float*)d_in[4];
    const float* Wa1  = (const float*)d_in[5];
    const float* ba1  = (const float*)d_in[6];
    const float* Wa2  = (const float*)d_in[7];
    // d_in[8]  = ba2  : unused (softmax shift-invariant)
    const float* Wih  = (const float*)d_in[9];
    // d_in[10] = W_hh : unused (h0 = 0)
    const float* bih  = (const float*)d_in[11];
    const float* bhh  = (const float*)d_in[12];
    const float* Wo1  = (const float*)d_in[13];
    const float* bo1  = (const float*)d_in[14];
    const float* Wo2  = (const float*)d_in[15];
    const float* bo2  = (const float*)d_in[16];
    const float* Wout = (const float*)d_in[17];
    const float* bout = (const float*)d_in[18];

    fused_kernel<<<dim3(BN), dim3(256), 0, stream>>>(
        x, Ws1, bs1, Ws2, bs2, Wa1, ba1, Wa2,
        Wih, bih, bhh, Wo1, bo1, Wo2, bo2, Wout, bout,
        (float*)d_out);
}

// Round 12
// 139.336 us; speedup vs baseline: 1.2434x; 1.0673x over previous
//
#include <hip/hip_runtime.h>

// Problem: B=32, N=128, T=96, H=64, TF=24. All I/O float32.
// A_norm = ones(N,N)/N => every GCN output is the node-mean (node-uniform);
// model collapses to per-batch H-vectors. Node dim only in the initial mean
// and the final broadcast.
//
// R11 (64us): packed-f16 register weights + readlane/dot2 matvec => chain is
// issue-bound, EXCEPT every __shfl_xor rides the LDS pipe (ds_swizzle,
// ~120-150cyc dependent). ~60K cyc of the profile was shuffle latency.
// R12: all cross-lane ops -> VALU DPP. xor1 pack = quad_perm[1,0,3,2]
// (0xB1). wave_sum/max = 4 DPP stages (0xB1, 0x4E, row_half_mirror 0x141,
// row_mirror 0x140) + 4 readlane + 3 adds (~60cyc, wave-uniform result).

#define BN 32
#define NN 128
#define TT 96
#define HH 64
#define TFC 24

#if defined(__has_builtin)
#if __has_builtin(__builtin_amdgcn_fdot2)
#define HAVE_FDOT2 1
#endif
#if __has_builtin(__builtin_amdgcn_update_dpp)
#define HAVE_DPP 1
#endif
#endif

using half2v = __fp16 __attribute__((ext_vector_type(2)));

__device__ __forceinline__ unsigned pack_pair(float a, float b) {
    union { half2v h; unsigned u; } c;
    c.h = __builtin_amdgcn_cvt_pkrtz(a, b);
    return c.u;
}
__device__ __forceinline__ half2v as_h2(unsigned u) {
    union { unsigned u; half2v h; } c; c.u = u; return c.h;
}
__device__ __forceinline__ unsigned rdlu(unsigned v, int l) {
    return (unsigned)__builtin_amdgcn_readlane((int)v, l);
}
__device__ __forceinline__ float rdl(float v, int l) {
    return __int_as_float(__builtin_amdgcn_readlane(__float_as_int(v), l));
}

template <int CTRL>
__device__ __forceinline__ float dppf(float x) {
#if HAVE_DPP
    return __int_as_float(
        __builtin_amdgcn_update_dpp(0, __float_as_int(x), CTRL, 0xF, 0xF, true));
#else
    return 0.f;  // unused
#endif
}

// xor-1 neighbor exchange: within-quad DPP (VALU pipe), not ds_swizzle.
__device__ __forceinline__ float xor1(float x) {
#if HAVE_DPP
    return dppf<0xB1>(x);          // quad_perm [1,0,3,2]
#else
    return __shfl_xor(x, 1, 64);
#endif
}

__device__ __forceinline__ float wave_sum(float v) {
#if HAVE_DPP
    v += dppf<0xB1>(v);            // xor1  (quad_perm [1,0,3,2])
    v += dppf<0x4E>(v);            // xor2  (quad_perm [2,3,0,1])
    v += dppf<0x141>(v);           // row_half_mirror: pairs quads within 8
    v += dppf<0x140>(v);           // row_mirror: pairs 8s within 16
    return ((rdl(v, 0) + rdl(v, 16)) + (rdl(v, 32) + rdl(v, 48)));
#else
#pragma unroll
    for (int off = 32; off > 0; off >>= 1) v += __shfl_xor(v, off, 64);
    return v;
#endif
}
__device__ __forceinline__ float wave_max(float v) {
#if HAVE_DPP
    v = fmaxf(v, dppf<0xB1>(v));
    v = fmaxf(v, dppf<0x4E>(v));
    v = fmaxf(v, dppf<0x141>(v));
    v = fmaxf(v, dppf<0x140>(v));
    return fmaxf(fmaxf(rdl(v, 0), rdl(v, 16)), fmaxf(rdl(v, 32), rdl(v, 48)));
#else
#pragma unroll
    for (int off = 32; off > 0; off >>= 1) v = fmaxf(v, __shfl_xor(v, off, 64));
    return v;
#endif
}

__device__ __forceinline__ float dot2acc(unsigned w, unsigned up, float acc) {
#if HAVE_FDOT2
    return __builtin_amdgcn_fdot2(as_h2(w), as_h2(up), acc, false);
#else
    const half2v wh = as_h2(w), uh = as_h2(up);
    return fmaf((float)wh.y, (float)uh.y, fmaf((float)wh.x, (float)uh.x, acc));
#endif
}

// 64-MAC matvec from packed-f16 register weights. UPACK holds (u[2k],u[2k+1])
// in even lane 2k (built once per matvec). Fully unrolled, constant indices.
#define PMV64(WP, UPACK, RES)                                              \
    do {                                                                   \
        float c0 = 0.f, c1 = 0.f, c2 = 0.f, c3 = 0.f;                      \
        _Pragma("unroll")                                                  \
        for (int k = 0; k < 32; k += 4) {                                  \
            c0 = dot2acc(WP[k],     rdlu(UPACK, 2 * k),     c0);           \
            c1 = dot2acc(WP[k + 1], rdlu(UPACK, 2 * k + 2), c1);           \
            c2 = dot2acc(WP[k + 2], rdlu(UPACK, 2 * k + 4), c2);           \
            c3 = dot2acc(WP[k + 3], rdlu(UPACK, 2 * k + 6), c3);           \
        }                                                                  \
        RES = (c0 + c1) + (c2 + c3);                                       \
    } while (0)

__device__ __forceinline__ float fast_tanh(float x) {
    x = fminf(fmaxf(x, -15.f), 15.f);
    float e = __expf(2.f * x);
    return 1.f - 2.f * __builtin_amdgcn_rcpf(e + 1.f);
}
__device__ __forceinline__ float fast_sigmoid(float x) {
    return __builtin_amdgcn_rcpf(1.f + __expf(-x));
}

__global__ __launch_bounds__(256)
__attribute__((amdgpu_waves_per_eu(1, 1)))
void fused_kernel(
    const float* __restrict__ x,    const float* __restrict__ Ws1,
    const float* __restrict__ bs1,  const float* __restrict__ Ws2,
    const float* __restrict__ bs2,  const float* __restrict__ Wa1,
    const float* __restrict__ ba1,  const float* __restrict__ Wa2,
    const float* __restrict__ Wih,  const float* __restrict__ bih,
    const float* __restrict__ bhh,  const float* __restrict__ Wo1,
    const float* __restrict__ bo1p, const float* __restrict__ Wo2,
    const float* __restrict__ bo2p, const float* __restrict__ Wout,
    const float* __restrict__ boutp, float* __restrict__ out)
{
    const int tid  = threadIdx.x;
    const int lane = tid & 63;
    const int w    = tid >> 6;
    const int b    = blockIdx.x;

    __shared__ float xbar[TT];
    __shared__ float h2s[TT][HH];
    __shared__ float atts[TT];

    // ---- phase 0: xbar[t] = mean_n x[b,n,t] (t-contiguous => coalesced) ----
    if (tid < TT) {
        const float* xb = x + (size_t)b * NN * TT + tid;
        float s = 0.f;
#pragma unroll
        for (int n = 0; n < NN; ++n) s += xb[n * TT];
        xbar[tid] = s * (1.f / 128.f);
    }

    {   // ---- phase 1: spatial GCN + attention logits, packed-f16 weights ----
        const float ws1l = Ws1[lane];
        const float bs1l = bs1[lane];
        const float bs2l = bs2[lane];
        const float ba1l = ba1[lane];
        const float wa2l = Wa2[lane];
        unsigned ws2p[32], wa1p[32];
#pragma unroll
        for (int k = 0; k < 32; ++k) {
            ws2p[k] = pack_pair(Ws2[(2 * k) * HH + lane], Ws2[(2 * k + 1) * HH + lane]);
            wa1p[k] = pack_pair(Wa1[(2 * k) * HH + lane], Wa1[(2 * k + 1) * HH + lane]);
        }
#pragma unroll
        for (int k = 0; k < 32; ++k) {
            asm volatile("" : "+v"(ws2p[k]), "+v"(wa1p[k]));  // pin: 64 VGPRs
        }
        __syncthreads();   // barrier 1: xbar ready

#pragma unroll 1
        for (int i = 0; i < TT / 4; ++i) {
            const int t = w * (TT / 4) + i;
            const float s = xbar[t];
            const float h1 = fmaxf(fmaf(s, ws1l, bs1l), 0.f);  // lane = h
            const unsigned up1 = pack_pair(h1, xor1(h1));
            float acc;
            PMV64(ws2p, up1, acc);
            const float h2v = fmaxf(acc + bs2l, 0.f);
            h2s[t][lane] = h2v;

            const unsigned up2 = pack_pair(h2v, xor1(h2v));
            PMV64(wa1p, up2, acc);
            const float g = fast_tanh(acc + ba1l);
            const float att = wave_sum(g * wa2l);   // ba2: shift-invariant
            if (lane == 0) atts[t] = att;
        }
    }
    __syncthreads();   // barrier 2: h2s, atts ready

    if (w != 0) return;   // waves 1-3 retire

    // ================= wave 0 only: softmax + nf + GRU + ODE =================
    const float a0s = atts[lane];
    const float a1s = (lane < TT - 64) ? atts[64 + lane] : -1e30f;
    const float m = wave_max(fmaxf(a0s, a1s));
    const float e0 = __expf(a0s - m);
    const float e1 = (lane < TT - 64) ? __expf(a1s - m) : 0.f;
    const float inv = __builtin_amdgcn_rcpf(wave_sum(e0 + e1));
    const float q0 = e0 * inv;
    const float q1 = e1 * inv;

    float nf = 0.f;
#pragma unroll
    for (int t = 0; t < 64; ++t) nf = fmaf(rdl(q0, t), h2s[t][lane], nf);
#pragma unroll
    for (int t = 0; t < 32; ++t) nf = fmaf(rdl(q1, t), h2s[64 + t][lane], nf);

    // one-step GRU, h0=0 (W_hh matmul vanishes; b_hh biases remain)
    float gr = bih[lane];
    float gz = bih[64 + lane];
    float gn = bih[128 + lane];
#pragma unroll
    for (int j = 0; j < HH; j += 4) {
        const float4 wr = *(const float4*)&Wih[(size_t)lane * HH + j];
        const float4 wz = *(const float4*)&Wih[(size_t)(64 + lane) * HH + j];
        const float4 wn = *(const float4*)&Wih[(size_t)(128 + lane) * HH + j];
        const float n0 = rdl(nf, j), n1 = rdl(nf, j + 1);
        const float n2 = rdl(nf, j + 2), n3 = rdl(nf, j + 3);
        gr += n0 * wr.x + n1 * wr.y + n2 * wr.z + n3 * wr.w;
        gz += n0 * wz.x + n1 * wz.y + n2 * wz.z + n3 * wz.w;
        gn += n0 * wn.x + n1 * wn.y + n2 * wn.z + n3 * wn.w;
    }
    const float r = fast_sigmoid(gr + bhh[lane]);
    const float z = fast_sigmoid(gz + bhh[64 + lane]);
    const float n = fast_tanh(gn + r * bhh[128 + lane]);
    float y = (1.f - z) * n;

    // ---- ODE weights: packed f16 into 64 pinned VGPRs (fits ~132 cap) ----
    unsigned w1p[32], w2p[32];
#pragma unroll
    for (int k = 0; k < 32; ++k) {
        w1p[k] = pack_pair(Wo1[(2 * k) * HH + lane], Wo1[(2 * k + 1) * HH + lane]);
        w2p[k] = pack_pair(Wo2[(2 * k) * HH + lane], Wo2[(2 * k + 1) * HH + lane]);
    }
#pragma unroll
    for (int k = 0; k < 32; ++k) {
        asm volatile("" : "+v"(w1p[k]), "+v"(w2p[k]));
    }
    const float bo1 = bo1p[lane];
    const float bo2 = bo2p[lane];
    const float wo  = Wout[lane];
    const float bo  = boutp[0];

    // f(u) = tanh( tanh(u@W1+b1) @ W2 + b2 ) — pure VALU, no memory, no LDS.
    auto f_eval = [&](float u) -> float {
        const unsigned upA = pack_pair(u, xor1(u));
        float acc;
        PMV64(w1p, upA, acc);
        const float v = fast_tanh(acc + bo1);
        const unsigned upB = pack_pair(v, xor1(v));
        PMV64(w2p, upB, acc);
        return fast_tanh(acc + bo2);
    };

    float* ob = out + (size_t)b * NN * TFC;
    {
        const float p = wave_sum(y * wo) + bo;     // traj[0] = hidden
        ob[lane * TFC]        = p;
        ob[(64 + lane) * TFC] = p;
    }

    const float dt = (float)(24.0 / 23.0);
    const float third = 1.f / 3.f;

#pragma unroll 1
    for (int st = 0; st < TFC - 1; ++st) {
        const float k1 = f_eval(y);
        const float k2 = f_eval(y + dt * k1 * third);
        const float k3 = f_eval(y + dt * (k2 - k1 * third));
        const float k4 = f_eval(y + dt * (k1 - k2 + k3));
        y = y + dt * (k1 + 3.f * (k2 + k3) + k4) * 0.125f;
        const float p = wave_sum(y * wo) + bo;
        ob[lane * TFC + st + 1]        = p;
        ob[(64 + lane) * TFC + st + 1] = p;
    }
}

extern "C" void kernel_launch(void* const* d_in, const int* in_sizes, int n_in,
                              void* d_out, int out_size, void* d_ws, size_t ws_size,
                              hipStream_t stream) {
    (void)in_sizes; (void)n_in; (void)d_ws; (void)ws_size; (void)out_size;
    const float* x    = (const float*)d_in[0];
    const float* Ws1  = (const float*)d_in[1];
    const float* bs1  = (const float*)d_in[2];
    const float* Ws2  = (const float*)d_in[3];
    const float* bs2  = (const float*)d_in[4];
    const float* Wa1  = (const float*)d_in[5];
    const float* ba1  = (const float*)d_in[6];
    const float* Wa2  = (const float*)d_in[7];
    // d_in[8]  = ba2  : unused (softmax shift-invariant)
    const float* Wih  = (const float*)d_in[9];
    // d_in[10] = W_hh : unused (h0 = 0)
    const float* bih  = (const float*)d_in[11];
    const float* bhh  = (const float*)d_in[12];
    const float* Wo1  = (const float*)d_in[13];
    const float* bo1  = (const float*)d_in[14];
    const float* Wo2  = (const float*)d_in[15];
    const float* bo2  = (const float*)d_in[16];
    const float* Wout = (const float*)d_in[17];
    const float* bout = (const float*)d_in[18];

    fused_kernel<<<dim3(BN), dim3(256), 0, stream>>>(
        x, Ws1, bs1, Ws2, bs2, Wa1, ba1, Wa2,
        Wih, bih, bhh, Wo1, bo1, Wo2, bo2, Wout, bout,
        (float*)d_out);
}

// Round 13
// 132.476 us; speedup vs baseline: 1.3078x; 1.0518x over previous
//
#include <hip/hip_runtime.h>

// Problem: B=32, N=128, T=96, H=64, TF=24. All I/O float32.
// A_norm = ones(N,N)/N => every GCN output is the node-mean (node-uniform);
// model collapses to per-batch H-vectors. Node dim only in the initial mean
// and the final broadcast.
//
// R12 (52us): packed-f16 register weights + readlane/dot2 + DPP reductions.
// Remaining 2.3x gap vs the ~22us issue model = SGPR read-after-write wait
// states (readlane->dot2 at distance 1) + zero cross-iteration ILP in
// phase 1. R13: (1) readlanes batched 8-ahead of their dot2 consumers;
// (2) phase 1 processes 2 t's per iteration with interleaved dual-stream
// matvec + wave_sum (shared weights => no VGPR cost); (3) tanh clamp
// dropped (limit behavior via exp/rcp is exact, finite inputs can't NaN).

#define BN 32
#define NN 128
#define TT 96
#define HH 64
#define TFC 24

#if defined(__has_builtin)
#if __has_builtin(__builtin_amdgcn_fdot2)
#define HAVE_FDOT2 1
#endif
#if __has_builtin(__builtin_amdgcn_update_dpp)
#define HAVE_DPP 1
#endif
#endif

using half2v = __fp16 __attribute__((ext_vector_type(2)));

__device__ __forceinline__ unsigned pack_pair(float a, float b) {
    union { half2v h; unsigned u; } c;
    c.h = __builtin_amdgcn_cvt_pkrtz(a, b);
    return c.u;
}
__device__ __forceinline__ half2v as_h2(unsigned u) {
    union { unsigned u; half2v h; } c; c.u = u; return c.h;
}
__device__ __forceinline__ unsigned rdlu(unsigned v, int l) {
    return (unsigned)__builtin_amdgcn_readlane((int)v, l);
}
__device__ __forceinline__ float rdl(float v, int l) {
    return __int_as_float(__builtin_amdgcn_readlane(__float_as_int(v), l));
}

template <int CTRL>
__device__ __forceinline__ float dppf(float x) {
#if HAVE_DPP
    return __int_as_float(
        __builtin_amdgcn_update_dpp(0, __float_as_int(x), CTRL, 0xF, 0xF, true));
#else
    return 0.f;  // unused
#endif
}

// xor-1 neighbor exchange on the VALU pipe (quad_perm [1,0,3,2]).
__device__ __forceinline__ float xor1(float x) {
#if HAVE_DPP
    return dppf<0xB1>(x);
#else
    return __shfl_xor(x, 1, 64);
#endif
}

__device__ __forceinline__ float wave_sum(float v) {
#if HAVE_DPP
    v += dppf<0xB1>(v);            // xor1
    v += dppf<0x4E>(v);            // xor2
    v += dppf<0x141>(v);           // row_half_mirror
    v += dppf<0x140>(v);           // row_mirror
    return ((rdl(v, 0) + rdl(v, 16)) + (rdl(v, 32) + rdl(v, 48)));
#else
#pragma unroll
    for (int off = 32; off > 0; off >>= 1) v += __shfl_xor(v, off, 64);
    return v;
#endif
}
// Two interleaved wave sums: the chains hide each other's DPP latency.
__device__ __forceinline__ void wave_sum2(float& a, float& b) {
#if HAVE_DPP
    a += dppf<0xB1>(a);  b += dppf<0xB1>(b);
    a += dppf<0x4E>(a);  b += dppf<0x4E>(b);
    a += dppf<0x141>(a); b += dppf<0x141>(b);
    a += dppf<0x140>(a); b += dppf<0x140>(b);
    a = (rdl(a, 0) + rdl(a, 16)) + (rdl(a, 32) + rdl(a, 48));
    b = (rdl(b, 0) + rdl(b, 16)) + (rdl(b, 32) + rdl(b, 48));
#else
    a = wave_sum(a); b = wave_sum(b);
#endif
}
__device__ __forceinline__ float wave_max(float v) {
#if HAVE_DPP
    v = fmaxf(v, dppf<0xB1>(v));
    v = fmaxf(v, dppf<0x4E>(v));
    v = fmaxf(v, dppf<0x141>(v));
    v = fmaxf(v, dppf<0x140>(v));
    return fmaxf(fmaxf(rdl(v, 0), rdl(v, 16)), fmaxf(rdl(v, 32), rdl(v, 48)));
#else
#pragma unroll
    for (int off = 32; off > 0; off >>= 1) v = fmaxf(v, __shfl_xor(v, off, 64));
    return v;
#endif
}

__device__ __forceinline__ float dot2acc(unsigned w, unsigned up, float acc) {
#if HAVE_FDOT2
    return __builtin_amdgcn_fdot2(as_h2(w), as_h2(up), acc, false);
#else
    const half2v wh = as_h2(w), uh = as_h2(up);
    return fmaf((float)wh.y, (float)uh.y, fmaf((float)wh.x, (float)uh.x, acc));
#endif
}

// 64-MAC matvec, readlanes batched 8-ahead (kills SGPR RAW wait states).
#define PMV64(WP, UPACK, RES)                                              \
    do {                                                                   \
        float c0 = 0.f, c1 = 0.f, c2 = 0.f, c3 = 0.f;                      \
        _Pragma("unroll")                                                  \
        for (int k = 0; k < 32; k += 8) {                                  \
            const unsigned u0 = rdlu(UPACK, 2 * k);                        \
            const unsigned u1 = rdlu(UPACK, 2 * k + 2);                    \
            const unsigned u2 = rdlu(UPACK, 2 * k + 4);                    \
            const unsigned u3 = rdlu(UPACK, 2 * k + 6);                    \
            const unsigned u4 = rdlu(UPACK, 2 * k + 8);                    \
            const unsigned u5 = rdlu(UPACK, 2 * k + 10);                   \
            const unsigned u6 = rdlu(UPACK, 2 * k + 12);                   \
            const unsigned u7 = rdlu(UPACK, 2 * k + 14);                   \
            c0 = dot2acc(WP[k],     u0, c0);                               \
            c1 = dot2acc(WP[k + 1], u1, c1);                               \
            c2 = dot2acc(WP[k + 2], u2, c2);                               \
            c3 = dot2acc(WP[k + 3], u3, c3);                               \
            c0 = dot2acc(WP[k + 4], u4, c0);                               \
            c1 = dot2acc(WP[k + 5], u5, c1);                               \
            c2 = dot2acc(WP[k + 6], u6, c2);                               \
            c3 = dot2acc(WP[k + 7], u7, c3);                               \
        }                                                                  \
        RES = (c0 + c1) + (c2 + c3);                                       \
    } while (0)

// Dual-stream 64-MAC matvec (shared weights): two independent chains
// interleaved => each hides the other's hazards/latency.
#define PMV64_2(WP, UA, UB, RA, RB)                                        \
    do {                                                                   \
        float a0 = 0.f, a1 = 0.f, a2 = 0.f, a3 = 0.f;                      \
        float b0 = 0.f, b1 = 0.f, b2 = 0.f, b3 = 0.f;                      \
        _Pragma("unroll")                                                  \
        for (int k = 0; k < 32; k += 4) {                                  \
            const unsigned ua0 = rdlu(UA, 2 * k);                          \
            const unsigned ub0 = rdlu(UB, 2 * k);                          \
            const unsigned ua1 = rdlu(UA, 2 * k + 2);                      \
            const unsigned ub1 = rdlu(UB, 2 * k + 2);                      \
            const unsigned ua2 = rdlu(UA, 2 * k + 4);                      \
            const unsigned ub2 = rdlu(UB, 2 * k + 4);                      \
            const unsigned ua3 = rdlu(UA, 2 * k + 6);                      \
            const unsigned ub3 = rdlu(UB, 2 * k + 6);                      \
            a0 = dot2acc(WP[k],     ua0, a0);                              \
            b0 = dot2acc(WP[k],     ub0, b0);                              \
            a1 = dot2acc(WP[k + 1], ua1, a1);                              \
            b1 = dot2acc(WP[k + 1], ub1, b1);                              \
            a2 = dot2acc(WP[k + 2], ua2, a2);                              \
            b2 = dot2acc(WP[k + 2], ub2, b2);                              \
            a3 = dot2acc(WP[k + 3], ua3, a3);                              \
            b3 = dot2acc(WP[k + 3], ub3, b3);                              \
        }                                                                  \
        RA = (a0 + a1) + (a2 + a3);                                        \
        RB = (b0 + b1) + (b2 + b3);                                        \
    } while (0)

// No clamp: x->+inf => e=inf => rcp=0 => 1; x->-inf => e=0 => 1-2 = -1.
__device__ __forceinline__ float fast_tanh(float x) {
    float e = __expf(2.f * x);
    return 1.f - 2.f * __builtin_amdgcn_rcpf(e + 1.f);
}
__device__ __forceinline__ float fast_sigmoid(float x) {
    return __builtin_amdgcn_rcpf(1.f + __expf(-x));
}

__global__ __launch_bounds__(256)
__attribute__((amdgpu_waves_per_eu(1, 1)))
void fused_kernel(
    const float* __restrict__ x,    const float* __restrict__ Ws1,
    const float* __restrict__ bs1,  const float* __restrict__ Ws2,
    const float* __restrict__ bs2,  const float* __restrict__ Wa1,
    const float* __restrict__ ba1,  const float* __restrict__ Wa2,
    const float* __restrict__ Wih,  const float* __restrict__ bih,
    const float* __restrict__ bhh,  const float* __restrict__ Wo1,
    const float* __restrict__ bo1p, const float* __restrict__ Wo2,
    const float* __restrict__ bo2p, const float* __restrict__ Wout,
    const float* __restrict__ boutp, float* __restrict__ out)
{
    const int tid  = threadIdx.x;
    const int lane = tid & 63;
    const int w    = tid >> 6;
    const int b    = blockIdx.x;

    __shared__ float xbar[TT];
    __shared__ float h2s[TT][HH];
    __shared__ float atts[TT];

    // ---- phase 0: xbar[t] = mean_n x[b,n,t] ----
    if (tid < TT) {
        const float* xb = x + (size_t)b * NN * TT + tid;
        float s = 0.f;
#pragma unroll
        for (int n = 0; n < NN; ++n) s += xb[n * TT];
        xbar[tid] = s * (1.f / 128.f);
    }

    {   // ---- phase 1: spatial GCN + attention logits, 2 t's per iter ----
        const float ws1l = Ws1[lane];
        const float bs1l = bs1[lane];
        const float bs2l = bs2[lane];
        const float ba1l = ba1[lane];
        const float wa2l = Wa2[lane];
        unsigned ws2p[32], wa1p[32];
#pragma unroll
        for (int k = 0; k < 32; ++k) {
            ws2p[k] = pack_pair(Ws2[(2 * k) * HH + lane], Ws2[(2 * k + 1) * HH + lane]);
            wa1p[k] = pack_pair(Wa1[(2 * k) * HH + lane], Wa1[(2 * k + 1) * HH + lane]);
        }
#pragma unroll
        for (int k = 0; k < 32; ++k) {
            asm volatile("" : "+v"(ws2p[k]), "+v"(wa1p[k]));  // pin: 64 VGPRs
        }
        __syncthreads();   // barrier 1: xbar ready

#pragma unroll 1
        for (int i = 0; i < TT / 8; ++i) {
            const int t0 = w * (TT / 4) + 2 * i;
            const int t1 = t0 + 1;
            const float sA = xbar[t0];
            const float sB = xbar[t1];
            const float h1A = fmaxf(fmaf(sA, ws1l, bs1l), 0.f);
            const float h1B = fmaxf(fmaf(sB, ws1l, bs1l), 0.f);
            const unsigned uA = pack_pair(h1A, xor1(h1A));
            const unsigned uB = pack_pair(h1B, xor1(h1B));
            float accA, accB;
            PMV64_2(ws2p, uA, uB, accA, accB);
            const float h2A = fmaxf(accA + bs2l, 0.f);
            const float h2B = fmaxf(accB + bs2l, 0.f);
            h2s[t0][lane] = h2A;
            h2s[t1][lane] = h2B;

            const unsigned vA = pack_pair(h2A, xor1(h2A));
            const unsigned vB = pack_pair(h2B, xor1(h2B));
            PMV64_2(wa1p, vA, vB, accA, accB);
            float gA = fast_tanh(accA + ba1l) * wa2l;
            float gB = fast_tanh(accB + ba1l) * wa2l;
            wave_sum2(gA, gB);                        // ba2: shift-invariant
            if (lane == 0) { atts[t0] = gA; atts[t1] = gB; }
        }
    }
    __syncthreads();   // barrier 2: h2s, atts ready

    if (w != 0) return;   // waves 1-3 retire

    // ================= wave 0 only: softmax + nf + GRU + ODE =================
    const float a0s = atts[lane];
    const float a1s = (lane < TT - 64) ? atts[64 + lane] : -1e30f;
    const float m = wave_max(fmaxf(a0s, a1s));
    const float e0 = __expf(a0s - m);
    const float e1 = (lane < TT - 64) ? __expf(a1s - m) : 0.f;
    const float inv = __builtin_amdgcn_rcpf(wave_sum(e0 + e1));
    const float q0 = e0 * inv;
    const float q1 = e1 * inv;

    float nf = 0.f;
#pragma unroll
    for (int t = 0; t < 64; ++t) nf = fmaf(rdl(q0, t), h2s[t][lane], nf);
#pragma unroll
    for (int t = 0; t < 32; ++t) nf = fmaf(rdl(q1, t), h2s[64 + t][lane], nf);

    // one-step GRU, h0=0 (W_hh matmul vanishes; b_hh biases remain)
    float gr = bih[lane];
    float gz = bih[64 + lane];
    float gn = bih[128 + lane];
#pragma unroll
    for (int j = 0; j < HH; j += 4) {
        const float4 wr = *(const float4*)&Wih[(size_t)lane * HH + j];
        const float4 wz = *(const float4*)&Wih[(size_t)(64 + lane) * HH + j];
        const float4 wn = *(const float4*)&Wih[(size_t)(128 + lane) * HH + j];
        const float n0 = rdl(nf, j), n1 = rdl(nf, j + 1);
        const float n2 = rdl(nf, j + 2), n3 = rdl(nf, j + 3);
        gr += n0 * wr.x + n1 * wr.y + n2 * wr.z + n3 * wr.w;
        gz += n0 * wz.x + n1 * wz.y + n2 * wz.z + n3 * wz.w;
        gn += n0 * wn.x + n1 * wn.y + n2 * wn.z + n3 * wn.w;
    }
    const float r = fast_sigmoid(gr + bhh[lane]);
    const float z = fast_sigmoid(gz + bhh[64 + lane]);
    const float n = fast_tanh(gn + r * bhh[128 + lane]);
    float y = (1.f - z) * n;

    // ---- ODE weights: packed f16 into 64 pinned VGPRs ----
    unsigned w1p[32], w2p[32];
#pragma unroll
    for (int k = 0; k < 32; ++k) {
        w1p[k] = pack_pair(Wo1[(2 * k) * HH + lane], Wo1[(2 * k + 1) * HH + lane]);
        w2p[k] = pack_pair(Wo2[(2 * k) * HH + lane], Wo2[(2 * k + 1) * HH + lane]);
    }
#pragma unroll
    for (int k = 0; k < 32; ++k) {
        asm volatile("" : "+v"(w1p[k]), "+v"(w2p[k]));
    }
    const float bo1 = bo1p[lane];
    const float bo2 = bo2p[lane];
    const float wo  = Wout[lane];
    const float bo  = boutp[0];

    // f(u) = tanh( tanh(u@W1+b1) @ W2 + b2 ) — pure VALU, batched readlanes.
    auto f_eval = [&](float u) -> float {
        const unsigned upA = pack_pair(u, xor1(u));
        float acc;
        PMV64(w1p, upA, acc);
        const float v = fast_tanh(acc + bo1);
        const unsigned upB = pack_pair(v, xor1(v));
        PMV64(w2p, upB, acc);
        return fast_tanh(acc + bo2);
    };

    float* ob = out + (size_t)b * NN * TFC;
    {
        const float p = wave_sum(y * wo) + bo;     // traj[0] = hidden
        ob[lane * TFC]        = p;
        ob[(64 + lane) * TFC] = p;
    }

    const float dt = (float)(24.0 / 23.0);
    const float third = 1.f / 3.f;

#pragma unroll 1
    for (int st = 0; st < TFC - 1; ++st) {
        const float k1 = f_eval(y);
        const float k2 = f_eval(y + dt * k1 * third);
        const float k3 = f_eval(y + dt * (k2 - k1 * third));
        const float k4 = f_eval(y + dt * (k1 - k2 + k3));
        y = y + dt * (k1 + 3.f * (k2 + k3) + k4) * 0.125f;
        const float p = wave_sum(y * wo) + bo;
        ob[lane * TFC + st + 1]        = p;
        ob[(64 + lane) * TFC + st + 1] = p;
    }
}

extern "C" void kernel_launch(void* const* d_in, const int* in_sizes, int n_in,
                              void* d_out, int out_size, void* d_ws, size_t ws_size,
                              hipStream_t stream) {
    (void)in_sizes; (void)n_in; (void)d_ws; (void)ws_size; (void)out_size;
    const float* x    = (const float*)d_in[0];
    const float* Ws1  = (const float*)d_in[1];
    const float* bs1  = (const float*)d_in[2];
    const float* Ws2  = (const float*)d_in[3];
    const float* bs2  = (const float*)d_in[4];
    const float* Wa1  = (const float*)d_in[5];
    const float* ba1  = (const float*)d_in[6];
    const float* Wa2  = (const float*)d_in[7];
    // d_in[8]  = ba2  : unused (softmax shift-invariant)
    const float* Wih  = (const float*)d_in[9];
    // d_in[10] = W_hh : unused (h0 = 0)
    const float* bih  = (const float*)d_in[11];
    const float* bhh  = (const float*)d_in[12];
    const float* Wo1  = (const float*)d_in[13];
    const float* bo1  = (const float*)d_in[14];
    const float* Wo2  = (const float*)d_in[15];
    const float* bo2  = (const float*)d_in[16];
    const float* Wout = (const float*)d_in[17];
    const float* bout = (const float*)d_in[18];

    fused_kernel<<<dim3(BN), dim3(256), 0, stream>>>(
        x, Ws1, bs1, Ws2, bs2, Wa1, ba1, Wa2,
        Wih, bih, bhh, Wo1, bo1, Wo2, bo2, Wout, bout,
        (float*)d_out);
}